// Round 23
// baseline (333.461 us; speedup 1.0000x reference)
//
#include <hip/hip_runtime.h>
#include <math.h>

#define NB 8
#define NT 2048
#define ND 512
#define NH 8
#define NDK 64
#define NL 512
#define NQKV 1536

typedef unsigned short u16;
typedef __attribute__((ext_vector_type(8))) short bf16x8;
typedef __attribute__((ext_vector_type(4))) float f32x4;

__device__ __forceinline__ float sigf(float v){ return 1.0f/(1.0f+__expf(-v)); }

__device__ __forceinline__ u16 f2b(float f){
  union{float f; unsigned u;} v; v.f = f;
  unsigned r = v.u + 0x7fffu + ((v.u>>16)&1u);
  return (u16)(r>>16);
}
__device__ __forceinline__ float b2f(u16 h){
  union{unsigned u; float f;} v; v.u = ((unsigned)h)<<16; return v.f;
}

#define GLOAD16(src, dst) \
  __builtin_amdgcn_global_load_lds((const __attribute__((address_space(1))) void*)(src), \
                                   (__attribute__((address_space(3))) void*)(dst), 16, 0, 0)

// ---------------- fused pool4 + LayerNorm + bf16 stream copy, f32 in ----------------
__global__ void k_poolcastln(const float* __restrict__ in, u16* __restrict__ xb,
                             u16* __restrict__ outb,
                             const float* __restrict__ gam, const float* __restrict__ bet){
  size_t prow = blockIdx.x;
  int lane = threadIdx.x;   // 64
  const float* p = in + prow*4*ND + lane*8;
  float x[8] = {0,0,0,0,0,0,0,0};
  #pragma unroll
  for(int rr=0;rr<4;rr++){
    float4 a = *(const float4*)&p[(size_t)rr*ND];
    float4 b = *(const float4*)&p[(size_t)rr*ND+4];
    uint4 pk;
    pk.x = (unsigned)f2b(a.x) | ((unsigned)f2b(a.y)<<16);
    pk.y = (unsigned)f2b(a.z) | ((unsigned)f2b(a.w)<<16);
    pk.z = (unsigned)f2b(b.x) | ((unsigned)f2b(b.y)<<16);
    pk.w = (unsigned)f2b(b.z) | ((unsigned)f2b(b.w)<<16);
    *(uint4*)&xb[(prow*4+rr)*ND + lane*8] = pk;
    x[0]+=a.x; x[1]+=a.y; x[2]+=a.z; x[3]+=a.w;
    x[4]+=b.x; x[5]+=b.y; x[6]+=b.z; x[7]+=b.w;
  }
  #pragma unroll
  for(int e=0;e<8;e++) x[e]*=0.25f;
  float s=0.f, ss=0.f;
  #pragma unroll
  for(int e=0;e<8;e++){ s+=x[e]; ss+=x[e]*x[e]; }
  #pragma unroll
  for(int o=32;o;o>>=1){ s+=__shfl_xor(s,o); ss+=__shfl_xor(ss,o); }
  float m  = s*(1.0f/ND);
  float rs = rsqrtf(ss*(1.0f/ND)-m*m+1e-5f);
  const float4* gp=(const float4*)gam; const float4* bp=(const float4*)bet;
  float4 g0=gp[lane*2],g1=gp[lane*2+1],b0=bp[lane*2],b1=bp[lane*2+1];
  float o0=(x[0]-m)*rs*g0.x+b0.x, o1=(x[1]-m)*rs*g0.y+b0.y;
  float o2=(x[2]-m)*rs*g0.z+b0.z, o3=(x[3]-m)*rs*g0.w+b0.w;
  float o4=(x[4]-m)*rs*g1.x+b1.x, o5=(x[5]-m)*rs*g1.y+b1.y;
  float o6=(x[6]-m)*rs*g1.z+b1.z, o7=(x[7]-m)*rs*g1.w+b1.w;
  uint4 pk;
  pk.x = (unsigned)f2b(o0) | ((unsigned)f2b(o1)<<16);
  pk.y = (unsigned)f2b(o2) | ((unsigned)f2b(o3)<<16);
  pk.z = (unsigned)f2b(o4) | ((unsigned)f2b(o5)<<16);
  pk.w = (unsigned)f2b(o6) | ((unsigned)f2b(o7)<<16);
  *(uint4*)&outb[prow*ND + lane*8] = pk;
}

// ---------------- fused pool4 + LayerNorm, bf16 in -> bf16 out ----------------
__global__ void k_poollnb(const u16* __restrict__ in, u16* __restrict__ outb,
                          const float* __restrict__ gam, const float* __restrict__ bet){
  size_t prow = blockIdx.x;
  int lane = threadIdx.x;
  const u16* p = in + prow*4*ND + lane*8;
  float x[8] = {0,0,0,0,0,0,0,0};
  #pragma unroll
  for(int rr=0;rr<4;rr++){
    ushort4 a = *(const ushort4*)&p[(size_t)rr*ND];
    ushort4 b = *(const ushort4*)&p[(size_t)rr*ND+4];
    x[0]+=b2f(a.x); x[1]+=b2f(a.y); x[2]+=b2f(a.z); x[3]+=b2f(a.w);
    x[4]+=b2f(b.x); x[5]+=b2f(b.y); x[6]+=b2f(b.z); x[7]+=b2f(b.w);
  }
  #pragma unroll
  for(int e=0;e<8;e++) x[e]*=0.25f;
  float s=0.f, ss=0.f;
  #pragma unroll
  for(int e=0;e<8;e++){ s+=x[e]; ss+=x[e]*x[e]; }
  #pragma unroll
  for(int o=32;o;o>>=1){ s+=__shfl_xor(s,o); ss+=__shfl_xor(ss,o); }
  float m  = s*(1.0f/ND);
  float rs = rsqrtf(ss*(1.0f/ND)-m*m+1e-5f);
  const float4* gp=(const float4*)gam; const float4* bp=(const float4*)bet;
  float4 g0=gp[lane*2],g1=gp[lane*2+1],b0=bp[lane*2],b1=bp[lane*2+1];
  float o0=(x[0]-m)*rs*g0.x+b0.x, o1=(x[1]-m)*rs*g0.y+b0.y;
  float o2=(x[2]-m)*rs*g0.z+b0.z, o3=(x[3]-m)*rs*g0.w+b0.w;
  float o4=(x[4]-m)*rs*g1.x+b1.x, o5=(x[5]-m)*rs*g1.y+b1.y;
  float o6=(x[6]-m)*rs*g1.z+b1.z, o7=(x[7]-m)*rs*g1.w+b1.w;
  uint4 pk;
  pk.x = (unsigned)f2b(o0) | ((unsigned)f2b(o1)<<16);
  pk.y = (unsigned)f2b(o2) | ((unsigned)f2b(o3)<<16);
  pk.z = (unsigned)f2b(o4) | ((unsigned)f2b(o5)<<16);
  pk.w = (unsigned)f2b(o6) | ((unsigned)f2b(o7)<<16);
  *(uint4*)&outb[prow*ND + lane*8] = pk;
}

// ---------------- row LayerNorm, bf16 in -> bf16 out, 4 rows/block ----------------
__global__ __launch_bounds__(256)
void k_lnb4(const u16* __restrict__ in, u16* __restrict__ outb,
            const float* __restrict__ gam, const float* __restrict__ bet){
  size_t row = (size_t)blockIdx.x*4 + (threadIdx.x>>6);
  int lane = threadIdx.x & 63;
  const u16* p = in + row*ND + lane*8;
  ushort4 a0 = *(const ushort4*)p;
  ushort4 a1 = *(const ushort4*)(p+4);
  float x0=b2f(a0.x),x1=b2f(a0.y),x2=b2f(a0.z),x3=b2f(a0.w);
  float x4=b2f(a1.x),x5=b2f(a1.y),x6=b2f(a1.z),x7=b2f(a1.w);
  float s  = x0+x1+x2+x3+x4+x5+x6+x7;
  float ss = x0*x0+x1*x1+x2*x2+x3*x3+x4*x4+x5*x5+x6*x6+x7*x7;
  #pragma unroll
  for(int o=32;o;o>>=1){ s+=__shfl_xor(s,o); ss+=__shfl_xor(ss,o); }
  float m  = s*(1.0f/ND);
  float rs = rsqrtf(ss*(1.0f/ND)-m*m+1e-5f);
  const float4* gp=(const float4*)gam; const float4* bp=(const float4*)bet;
  float4 g0=gp[lane*2],g1=gp[lane*2+1],b0=bp[lane*2],b1=bp[lane*2+1];
  float o0=(x0-m)*rs*g0.x+b0.x, o1=(x1-m)*rs*g0.y+b0.y;
  float o2=(x2-m)*rs*g0.z+b0.z, o3=(x3-m)*rs*g0.w+b0.w;
  float o4=(x4-m)*rs*g1.x+b1.x, o5=(x5-m)*rs*g1.y+b1.y;
  float o6=(x6-m)*rs*g1.z+b1.z, o7=(x7-m)*rs*g1.w+b1.w;
  uint4 pk;
  pk.x = (unsigned)f2b(o0) | ((unsigned)f2b(o1)<<16);
  pk.y = (unsigned)f2b(o2) | ((unsigned)f2b(o3)<<16);
  pk.z = (unsigned)f2b(o4) | ((unsigned)f2b(o5)<<16);
  pk.w = (unsigned)f2b(o6) | ((unsigned)f2b(o7)<<16);
  *(uint4*)&outb[row*ND + lane*8] = pk;
}

// ---------------- bias concat: [bq|bk|bv] -> 1536 f32 ----------------
__global__ void k_cat3(const float* __restrict__ a, const float* __restrict__ b,
                       const float* __restrict__ c, float* __restrict__ o){
  int t = blockIdx.x*256 + threadIdx.x;
  if(t >= 1536) return;
  o[t] = t < 512 ? a[t] : (t < 1024 ? b[t-512] : c[t-1024]);
}

// ---------------- merged weight transpose+cast: 13 jobs, one launch ----------------
struct WtJobs {
  const float* W[13];
  u16* WT[13];
  int K[13], N[13];
  int off[14];
};
__global__ __launch_bounds__(256)
void k_wt_all(WtJobs jobs){
  __shared__ float ls[32][33];
  int bid = blockIdx.x;
  int ji = 0;
  #pragma unroll
  for(int t=0;t<12;t++) if(bid >= jobs.off[t+1]) ji = t+1;
  int local = bid - jobs.off[ji];
  const float* W = jobs.W[ji];
  u16* WT = jobs.WT[ji];
  int K = jobs.K[ji], N = jobs.N[ji];
  int tn = N>>5;
  int n0 = (local % tn)*32, k0 = (local / tn)*32;
  int tid = threadIdx.x;
  int tx = tid&31, ty = tid>>5;
  #pragma unroll
  for(int p=0;p<4;p++)
    ls[ty+p*8][tx] = W[(size_t)(k0+ty+p*8)*N + n0+tx];
  __syncthreads();
  #pragma unroll
  for(int p=0;p<4;p++)
    WT[(size_t)(n0+ty+p*8)*K + k0+tx] = f2b(ls[tx][ty+p*8]);
}

// =======================================================================
// MFMA GEMM (generic): C = A_bf16[M,K] @ BT_bf16[N,K]^T (+ epilogue)
// BK=64, 128B LDS rows with 8-chunk XOR involution (chunk c at c^(row&7)).
// MI in {1,2,4} -> BM = 32/64/128.
// =======================================================================
template<int EPI, int MI>
__global__ __launch_bounds__(256, 3)
void k_gemm_mfma(const u16* __restrict__ A, const u16* __restrict__ BT,
                 const float* __restrict__ bias,
                 const u16* __restrict__ xinB, const u16* __restrict__ upB,
                 float* __restrict__ outF, u16* __restrict__ outB,
                 int M, int N, int K){
  constexpr int BM = MI*32;
  __shared__ short lA[BM*64];
  __shared__ short lB[128*64];
  int tid = threadIdx.x;
  int wv_ = tid>>6, ln_ = tid&63;
  int wy = wv_>>1, wx = wv_&1;
  int nx = gridDim.x;
  int flat = blockIdx.y*nx + blockIdx.x;
  int cpx = (nx*gridDim.y)>>3;
  int swz = (flat&7)*cpx + (flat>>3);
  int m0 = (swz/nx)*BM, n0 = (swz%nx)*128;

  f32x4 acc[MI][4];
  #pragma unroll
  for(int i=0;i<MI;i++)
    #pragma unroll
    for(int j=0;j<4;j++){ f32x4 z = {0.f,0.f,0.f,0.f}; acc[i][j]=z; }

  int fr = ln_&15, kg = ln_>>4;

  for(int k0=0;k0<K;k0+=64){
    #pragma unroll
    for(int q=0;q<MI;q++){
      int s = q*256 + tid;
      int row = s>>3;
      int gl = (s&7) ^ (row&7);
      GLOAD16(A + (size_t)(m0+row)*K + k0 + gl*8, &lA[s*8]);
    }
    #pragma unroll
    for(int q=0;q<4;q++){
      int s = q*256 + tid;
      int row = s>>3;
      int gl = (s&7) ^ (row&7);
      GLOAD16(BT + (size_t)(n0+row)*K + k0 + gl*8, &lB[s*8]);
    }
    __syncthreads();
    #pragma unroll
    for(int kk=0;kk<2;kk++){
      bf16x8 af[MI], bf[4];
      #pragma unroll
      for(int i=0;i<MI;i++){
        int ar = wy*(MI*16) + i*16 + fr;
        af[i] = *(const bf16x8*)((const char*)lA + ar*128 + (((kk*4+kg) ^ (ar&7))<<4));
      }
      #pragma unroll
      for(int j=0;j<4;j++){
        int br = wx*64 + j*16 + fr;
        bf[j] = *(const bf16x8*)((const char*)lB + br*128 + (((kk*4+kg) ^ (br&7))<<4));
      }
      #pragma unroll
      for(int i=0;i<MI;i++)
        #pragma unroll
        for(int j=0;j<4;j++)
          acc[i][j] = __builtin_amdgcn_mfma_f32_16x16x32_bf16(af[i], bf[j], acc[i][j], 0,0,0);
    }
    __syncthreads();
  }

  int r0 = (ln_>>4)*4, c0 = ln_&15;
  #pragma unroll
  for(int i=0;i<MI;i++){
    #pragma unroll
    for(int j=0;j<4;j++){
      int gr = m0 + wy*(MI*16) + i*16 + r0;
      int gc = n0 + wx*64 + j*16 + c0;
      float bv = bias[gc];
      #pragma unroll
      for(int r=0;r<4;r++){
        float val = acc[i][j][r] + bv;
        size_t idx = (size_t)(gr+r)*N + gc;
        float o;
        if(EPI==0){
          o = val;
        } else if(EPI==1){
          o = b2f(xinB[idx]) + sigf(val)*b2f(upB[(size_t)((gr+r)>>2)*N + gc]);
        } else {
          o = b2f(xinB[idx]) + val;
        }
        if(outF) outF[idx] = o;
        if(outB) outB[idx] = f2b(o);
      }
    }
  }
}

// =======================================================================
// MFMA GLU GEMM — BK=64
// =======================================================================
__global__ __launch_bounds__(256, 3)
void k_glu_mfma(const u16* __restrict__ A, const u16* __restrict__ WT,
                const float* __restrict__ bias, u16* __restrict__ outB,
                int M, int Dh, int K){
  __shared__ short lA [128*64];
  __shared__ short lBa[64*64];
  __shared__ short lBb[64*64];
  int tid = threadIdx.x;
  int wv_ = tid>>6, ln_ = tid&63;
  int wy = wv_>>1, wx = wv_&1;
  int nx = gridDim.x;
  int flat = blockIdx.y*nx + blockIdx.x;
  int cpx = (nx*gridDim.y)>>3;
  int swz = (flat&7)*cpx + (flat>>3);
  int m0 = (swz/nx)*128, n0 = (swz%nx)*64;

  f32x4 aca[4][2], acb[4][2];
  #pragma unroll
  for(int i=0;i<4;i++)
    #pragma unroll
    for(int j=0;j<2;j++){ f32x4 z={0.f,0.f,0.f,0.f}; aca[i][j]=z; acb[i][j]=z; }

  int fr = ln_&15, kg = ln_>>4;

  for(int k0=0;k0<K;k0+=64){
    #pragma unroll
    for(int q=0;q<4;q++){
      int s = q*256 + tid;
      int row = s>>3;
      int gl = (s&7) ^ (row&7);
      GLOAD16(A + (size_t)(m0+row)*K + k0 + gl*8, &lA[s*8]);
    }
    #pragma unroll
    for(int q=0;q<2;q++){
      int s = q*256 + tid;
      int row = s>>3;
      int gl = (s&7) ^ (row&7);
      GLOAD16(WT + (size_t)(n0+row)*K    + k0 + gl*8, &lBa[s*8]);
      GLOAD16(WT + (size_t)(Dh+n0+row)*K + k0 + gl*8, &lBb[s*8]);
    }
    __syncthreads();
    #pragma unroll
    for(int kk=0;kk<2;kk++){
      bf16x8 af[4], ba[2], bb[2];
      #pragma unroll
      for(int i=0;i<4;i++){
        int ar = wy*64 + i*16 + fr;
        af[i] = *(const bf16x8*)((const char*)lA + ar*128 + (((kk*4+kg) ^ (ar&7))<<4));
      }
      #pragma unroll
      for(int j=0;j<2;j++){
        int br = wx*32 + j*16 + fr;
        int off = br*128 + (((kk*4+kg) ^ (br&7))<<4);
        ba[j] = *(const bf16x8*)((const char*)lBa + off);
        bb[j] = *(const bf16x8*)((const char*)lBb + off);
      }
      #pragma unroll
      for(int i=0;i<4;i++)
        #pragma unroll
        for(int j=0;j<2;j++){
          aca[i][j] = __builtin_amdgcn_mfma_f32_16x16x32_bf16(af[i], ba[j], aca[i][j], 0,0,0);
          acb[i][j] = __builtin_amdgcn_mfma_f32_16x16x32_bf16(af[i], bb[j], acb[i][j], 0,0,0);
        }
    }
    __syncthreads();
  }

  int r0 = (ln_>>4)*4, c0 = ln_&15;
  #pragma unroll
  for(int i=0;i<4;i++){
    #pragma unroll
    for(int j=0;j<2;j++){
      int gr = m0 + wy*64 + i*16 + r0;
      int gc = n0 + wx*32 + j*16 + c0;
      float bva = bias[gc], bvb = bias[Dh+gc];
      #pragma unroll
      for(int r=0;r<4;r++){
        float o = (aca[i][j][r]+bva) * sigf(acb[i][j][r]+bvb);
        outB[(size_t)(gr+r)*Dh + gc] = f2b(o);
      }
    }
  }
}

// =======================================================================
// MFMA QK^T — single BK=64 step. q/k from fused qkv [row][1536].
// =======================================================================
__global__ __launch_bounds__(256, 3)
void k_qkt_mfma(const u16* __restrict__ qkv, u16* __restrict__ SC){
  int z = blockIdx.z, b = z>>3, h = z&7;
  int i0 = blockIdx.y*128, j0 = blockIdx.x*128;
  __shared__ short lA[128*64];
  __shared__ short lB[128*64];
  int tid = threadIdx.x;
  int wv_ = tid>>6, ln_ = tid&63;
  int wy = wv_>>1, wx = wv_&1;
  const u16* Ab = qkv + ((size_t)b*NL + i0)*NQKV + h*NDK;
  const u16* Bb = qkv + ((size_t)b*NL + j0)*NQKV + 512 + h*NDK;

  f32x4 acc[4][4];
  #pragma unroll
  for(int i=0;i<4;i++)
    #pragma unroll
    for(int j=0;j<4;j++){ f32x4 zz={0.f,0.f,0.f,0.f}; acc[i][j]=zz; }

  int fr = ln_&15, kg = ln_>>4;

  #pragma unroll
  for(int q=0;q<4;q++){
    int s = q*256 + tid;
    int row = s>>3;
    int gl = (s&7) ^ (row&7);
    GLOAD16(Ab + (size_t)row*NQKV + gl*8, &lA[s*8]);
    GLOAD16(Bb + (size_t)row*NQKV + gl*8, &lB[s*8]);
  }
  __syncthreads();
  #pragma unroll
  for(int kk=0;kk<2;kk++){
    bf16x8 af[4], bf[4];
    #pragma unroll
    for(int i=0;i<4;i++){
      int ar = wy*64 + i*16 + fr;
      af[i] = *(const bf16x8*)((const char*)lA + ar*128 + (((kk*4+kg) ^ (ar&7))<<4));
    }
    #pragma unroll
    for(int j=0;j<4;j++){
      int br = wx*64 + j*16 + fr;
      bf[j] = *(const bf16x8*)((const char*)lB + br*128 + (((kk*4+kg) ^ (br&7))<<4));
    }
    #pragma unroll
    for(int i=0;i<4;i++)
      #pragma unroll
      for(int j=0;j<4;j++)
        acc[i][j] = __builtin_amdgcn_mfma_f32_16x16x32_bf16(af[i], bf[j], acc[i][j], 0,0,0);
  }

  u16* sb = SC + (size_t)z*NL*NL;
  int r0 = (ln_>>4)*4, c0 = ln_&15;
  #pragma unroll
  for(int i=0;i<4;i++){
    #pragma unroll
    for(int j=0;j<4;j++){
      int gr = i0 + wy*64 + i*16 + r0;
      int gc = j0 + wx*64 + j*16 + c0;
      #pragma unroll
      for(int r=0;r<4;r++)
        sb[(size_t)(gr+r)*NL + gc] = f2b(acc[i][j][r]);
    }
  }
}

// =======================================================================
// MFMA Bm + softmax — R23: SC seed staged through LDS (coalesced uint4)
// instead of 128 scalar 2B global loads per thread. Math/layout unchanged.
// =======================================================================
__global__ __launch_bounds__(256, 2)
void k_bmsm_mfma(const u16* __restrict__ SC, const u16* __restrict__ qkv,
                 const float* __restrict__ pos, u16* __restrict__ P){
  int i = blockIdx.x;
  __shared__ u16 posB[512*64];   // 64 KB: SC seed stage -> pos bf16 -> P repack
  int tid = threadIdx.x;
  int w = tid>>6, ln = tid&63;
  int fr = ln&15, kg = ln>>4;
  const float* pp = pos + (size_t)i*NL*NDK;

  // ---- phase 0: stage SC rows [64 bh][512 j] into LDS, coalesced ----
  #pragma unroll
  for(int t0=0;t0<16;t0++){
    int t = t0*256 + tid;          // 4096 uint4 = 64 rows x 64
    int bh = t>>6, j8 = (t&63)*8;
    *(uint4*)&posB[bh*512 + j8] = *(const uint4*)&SC[((size_t)bh*NL + i)*NL + j8];
  }
  // A fragments (global, L3-hot) while SC stage is in flight
  bf16x8 af[2];
  #pragma unroll
  for(int kk=0;kk<2;kk++){
    int bh = w*16 + fr;
    af[kk] = *(const bf16x8*)(qkv + ((size_t)(bh>>3)*NL + i)*NQKV + (bh&7)*NDK + kk*32 + kg*8);
  }
  __syncthreads();
  // seed acc from LDS (2B reads; fr-pairs share dwords -> broadcast)
  f32x4 acc[2][16];
  #pragma unroll
  for(int H=0;H<2;H++)
    #pragma unroll
    for(int r=0;r<4;r++){
      int bh = w*16 + kg*4 + r;
      #pragma unroll
      for(int nj=0;nj<16;nj++)
        acc[H][nj][r] = b2f(posB[bh*512 + H*256 + nj*16 + fr]);
    }
  __syncthreads();   // seed reads done -> safe to overwrite with pos

  // ---- phase 1: reg-stage pos as bf16, chunk-swizzled ----
  #pragma unroll
  for(int rr=0;rr<2;rr++){
    int j = rr*256 + tid;
    const float* rp = pp + (size_t)j*64;
    #pragma unroll
    for(int c=0;c<8;c++){
      float4 a = *(const float4*)&rp[c*8];
      float4 b = *(const float4*)&rp[c*8+4];
      uint4 pk;
      pk.x = (unsigned)f2b(a.x) | ((unsigned)f2b(a.y)<<16);
      pk.y = (unsigned)f2b(a.z) | ((unsigned)f2b(a.w)<<16);
      pk.z = (unsigned)f2b(b.x) | ((unsigned)f2b(b.y)<<16);
      pk.w = (unsigned)f2b(b.z) | ((unsigned)f2b(b.w)<<16);
      int cw = c ^ (j&7);
      *(uint4*)((char*)posB + j*128 + cw*16) = pk;
    }
  }
  __syncthreads();

  // ---- MFMA: B-frag = one 16B ds_read, no conversion ----
  #pragma unroll
  for(int H=0;H<2;H++)
    #pragma unroll
    for(int nj=0;nj<16;nj++){
      int j = H*256 + nj*16 + fr;
      #pragma unroll
      for(int kk=0;kk<2;kk++){
        int cw = (kk*4 + kg) ^ (j&7);
        bf16x8 bfrag = *(const bf16x8*)((const char*)posB + j*128 + (cw<<4));
        acc[H][nj] = __builtin_amdgcn_mfma_f32_16x16x32_bf16(af[kk], bfrag, acc[H][nj], 0,0,0);
      }
    }

  // ---- wave-local softmax over 512 j per row ----
  float inv_[4];
  #pragma unroll
  for(int r=0;r<4;r++){
    float m = -3e38f;
    #pragma unroll
    for(int H=0;H<2;H++)
      #pragma unroll
      for(int nj=0;nj<16;nj++){
        acc[H][nj][r] *= 0.125f;
        m = fmaxf(m, acc[H][nj][r]);
      }
    #pragma unroll
    for(int o=8;o;o>>=1) m = fmaxf(m, __shfl_xor(m,o));
    float s = 0.f;
    #pragma unroll
    for(int H=0;H<2;H++)
      #pragma unroll
      for(int nj=0;nj<16;nj++){
        acc[H][nj][r] = __expf(acc[H][nj][r] - m);
        s += acc[H][nj][r];
      }
    #pragma unroll
    for(int o=8;o;o>>=1) s += __shfl_xor(s,o);
    inv_[r] = 1.0f/s;
  }

  __syncthreads();   // all posB reads done -> safe to overwrite with P
  u16* Pls = posB;
  #pragma unroll
  for(int r=0;r<4;r++){
    int bh = w*16 + kg*4 + r;
    #pragma unroll
    for(int H=0;H<2;H++)
      #pragma unroll
      for(int nj=0;nj<16;nj++)
        Pls[bh*512 + H*256 + nj*16 + fr] = f2b(acc[H][nj][r]*inv_[r]);
  }
  __syncthreads();
  #pragma unroll
  for(int t0=0;t0<16;t0++){
    int t = t0*256 + tid;
    int bh = t>>6, j8 = (t&63)*8;
    uint4 v = *(const uint4*)&Pls[bh*512 + j8];
    *(uint4*)&P[((size_t)bh*NL + i)*NL + j8] = v;
  }
}

// =======================================================================
// MFMA PV — BM=64; v from fused qkv
// =======================================================================
__global__ __launch_bounds__(256, 3)
void k_pv_mfma(const u16* __restrict__ P, const u16* __restrict__ qkv,
               u16* __restrict__ o){
  int z = blockIdx.y, b = z>>3, h = z&7;
  int i0 = blockIdx.x*64;
  __shared__ short lA[64*32];
  __shared__ short lBt[64*64];
  int tid = threadIdx.x;
  int wv_ = tid>>6, ln_ = tid&63;
  int wy = wv_>>1, wx = wv_&1;
  const u16* Ab = P + ((size_t)z*NL + i0)*NL;
  const u16* vb = qkv + (size_t)b*NL*NQKV + 1024 + h*NDK;   // v

  f32x4 acc[2][2];
  #pragma unroll
  for(int mi=0;mi<2;mi++)
    #pragma unroll
    for(int nj=0;nj<2;nj++){ f32x4 zz={0.f,0.f,0.f,0.f}; acc[mi][nj]=zz; }

  int fr = ln_&15, kg = ln_>>4;
  int aoff[2];
  #pragma unroll
  for(int mi=0;mi<2;mi++){
    int ar = wy*32 + mi*16 + fr;
    aoff[mi] = ar*64 + ((kg ^ ((ar>>1)&3))<<4);
  }
  int boff[2];
  #pragma unroll
  for(int nj=0;nj<2;nj++){
    int n = wx*32 + nj*16 + fr;
    boff[nj] = (n*128 + kg*16) ^ ((n&7)<<4);
  }
  int jrow = tid>>3, d8 = (tid&7)*8;

  for(int k0=0;k0<NL;k0+=32){
    {
      int s = tid;
      int row = s>>2;
      int gl = (s&3) ^ ((row>>1)&3);
      GLOAD16(Ab + (size_t)row*NL + k0 + gl*8, &lA[wv_*512]);
    }
    {
      uint4 v = *(const uint4*)&vb[(size_t)(k0 + jrow)*NQKV + d8];
      u16 e[8];
      e[0]=(u16)(v.x&0xffff); e[1]=(u16)(v.x>>16);
      e[2]=(u16)(v.y&0xffff); e[3]=(u16)(v.y>>16);
      e[4]=(u16)(v.z&0xffff); e[5]=(u16)(v.z>>16);
      e[6]=(u16)(v.w&0xffff); e[7]=(u16)(v.w>>16);
      #pragma unroll
      for(int ee=0;ee<8;ee++){
        int d = d8+ee;
        int byt = (d*128 + jrow*2) ^ ((d&7)<<4);
        *(u16*)((char*)lBt + byt) = e[ee];
      }
    }
    __syncthreads();
    bf16x8 af[2], bf[2];
    #pragma unroll
    for(int mi=0;mi<2;mi++) af[mi] = *(const bf16x8*)((const char*)lA + aoff[mi]);
    #pragma unroll
    for(int nj=0;nj<2;nj++) bf[nj] = *(const bf16x8*)((const char*)lBt + boff[nj]);
    #pragma unroll
    for(int mi=0;mi<2;mi++)
      #pragma unroll
      for(int nj=0;nj<2;nj++)
        acc[mi][nj] = __builtin_amdgcn_mfma_f32_16x16x32_bf16(af[mi], bf[nj], acc[mi][nj], 0,0,0);
    __syncthreads();
  }

  int r0 = (ln_>>4)*4;
  #pragma unroll
  for(int mi=0;mi<2;mi++){
    #pragma unroll
    for(int nj=0;nj<2;nj++){
      #pragma unroll
      for(int r=0;r<4;r++){
        int gi = i0 + wy*32 + mi*16 + r0 + r;
        int gd = wx*32 + nj*16 + fr;
        o[((size_t)b*NL + gi)*ND + h*NDK + gd] = f2b(acc[mi][nj][r]);
      }
    }
  }
}

// =======================================================================
// depthwise conv1d, K=31, SAME — LDS-tiled; R23: 3 blocks/CU
// =======================================================================
__global__ __launch_bounds__(256, 3)
void k_dwconv(const u16* __restrict__ in, const float* __restrict__ w,
              const float* __restrict__ bias, u16* __restrict__ out){
  __shared__ u16 tile[94][64];
  int c0 = blockIdx.x*64;
  int t0 = blockIdx.y*64;
  int b  = blockIdx.z;
  int tid = threadIdx.x;
  const u16* ib = in + (size_t)b*NT*ND + c0;
  for(int s = tid; s < 94*16; s += 256){
    int r  = s >> 4;
    int cc = (s & 15) * 4;
    int t  = t0 - 15 + r;
    uint2 v = make_uint2(0u, 0u);
    if(t >= 0 && t < NT) v = *(const uint2*)&ib[(size_t)t*ND + cc];
    *(uint2*)&tile[r][cc] = v;
  }
  __syncthreads();
  int c  = tid & 63;
  int tg = tid >> 6;
  float wg[31];
  #pragma unroll
  for(int kk=0;kk<31;kk++) wg[kk] = w[(c0+c)*31+kk];
  float bs = bias[c0+c];
  float win[46];
  #pragma unroll
  for(int r=0;r<46;r++) win[r] = b2f(tile[tg*16 + r][c]);
  u16* ob = out + (size_t)b*NT*ND + (size_t)(t0 + tg*16)*ND + c0 + c;
  #pragma unroll
  for(int oo=0;oo<16;oo++){
    float s = bs;
    #pragma unroll
    for(int kk=0;kk<31;kk++) s += win[oo+kk]*wg[kk];
    ob[(size_t)oo*ND] = f2b(s);
  }
}

extern "C" void kernel_launch(void* const* d_in, const int* in_sizes, int n_in,
                              void* d_out, int out_size, void* d_ws, size_t ws_size,
                              hipStream_t stream) {
  const float* x      = (const float*)d_in[0];
  const float* pos    = (const float*)d_in[1];
  const float* mha_g  = (const float*)d_in[2];
  const float* mha_b  = (const float*)d_in[3];
  const float* wq     = (const float*)d_in[4];
  const float* bq     = (const float*)d_in[5];
  const float* wk     = (const float*)d_in[6];
  const float* bk     = (const float*)d_in[7];
  const float* wv     = (const float*)d_in[8];
  const float* bv     = (const float*)d_in[9];
  const float* wo     = (const float*)d_in[10];
  const float* bo     = (const float*)d_in[11];
  const float* ega_wg = (const float*)d_in[12];
  const float* ega_bg = (const float*)d_in[13];
  const float* g1_ln_g= (const float*)d_in[14];
  const float* g1_ln_b= (const float*)d_in[15];
  const float* g1_w1  = (const float*)d_in[16];
  const float* g1_b1  = (const float*)d_in[17];
  const float* g1_w2  = (const float*)d_in[18];
  const float* g1_b2  = (const float*)d_in[19];
  const float* g1_wg  = (const float*)d_in[20];
  const float* g1_bg  = (const float*)d_in[21];
  const float* cla_ln_g=(const float*)d_in[22];
  const float* cla_ln_b=(const float*)d_in[23];
  const float* cla_w1 = (const float*)d_in[24];
  const float* cla_b1 = (const float*)d_in[25];
  const float* dw_w   = (const float*)d_in[26];
  const float* dw_b   = (const float*)d_in[27];
  const float* cla_w2 = (const float*)d_in[28];
  const float* cla_b2 = (const float*)d_in[29];
  const float* g2_ln_g= (const float*)d_in[30];
  const float* g2_ln_b= (const float*)d_in[31];
  const float* g2_w1  = (const float*)d_in[32];
  const float* g2_b1  = (const float*)d_in[33];
  const float* g2_w2  = (const float*)d_in[34];
  const float* g2_b2  = (const float*)d_in[35];
  const float* g2_wg  = (const float*)d_in[36];
  const float* g2_bg  = (const float*)d_in[37];

  float* xo = (float*)d_out;
  float* ws = (float*)d_ws;
  const size_t M1 = 1024*1024;

  u16*  SCb    = (u16*)ws;                 // scores bf16 [0,8M) (attn phase)
  u16*  s5b    = (u16*)ws;                 // [0,1)   attn out bf16
  u16*  glu_p  = (u16*)ws;                 // [0,6)   g1/g2 GLU out
  u16*  glu_b  = (u16*)ws;                 // [0,4)   CLA GLU out
  u16*  conv_b = (u16*)(ws + 4*M1);        // [4,8)   CLA conv out
  u16*  s6b    = (u16*)(ws + 6*M1);        // [6,7)   'up' bf16
  u16*  lnPb   = (u16*)(ws + 7*M1);        // [7,8)   pooled ln bf16
  u16*  lnFb   = (u16*)(ws + 8*M1);        // [8,12)  CLA ln bf16
  u16*  Pb     = (u16*)(ws + 16*M1);       // [16,24) attn probs bf16
  u16*  xbA    = (u16*)(ws + 24*M1);       // [24,28) stream ping
  u16*  xbB    = (u16*)(ws + 28*M1);       // [28,32) stream pong
  u16*  WTb    = (u16*)(ws + 32*M1);       // [32,36) bf16 weights
  u16*  qkv    = (u16*)(ws + 38*M1);       // [38,41) fused qkv bf16 [4096][1536]
  float* bias_qkv = ws + 41*M1;            // 1536 f32

  u16* wqT   = WTb + 0;
  u16* wkT   = WTb + 262144;
  u16* wvT   = WTb + 524288;
  u16* woT   = WTb + 786432;
  u16* egaT  = WTb + 1048576;
  u16* g1w1T = WTb + 1310720;
  u16* g1w2T = WTb + 2883584;
  u16* g1wgT = WTb + 3670016;
  u16* claw1T= WTb + 3932160;
  u16* claw2T= WTb + 4456448;
  u16* g2w1T = WTb + 4718592;
  u16* g2w2T = WTb + 6291456;
  u16* g2wgT = WTb + 7077888;

  const int rowsP = NB*NL;        // 4096
  const int rowsF = NB*NT;        // 16384
  dim3 blk(256);
  dim3 gPool1(4,128);             // pooled GEMM (N=512): BM=32 -> 512 blocks, 2/CU
  dim3 gQKV(12,64);               // pooled GEMM (N=1536): BM=64 -> 768 blocks
  dim3 gFull2(4,256);             // full-T GEMM: BM=64 -> 1024 blocks

  // ---- weight prep ----
  {
    WtJobs J;
    const float* Wsrc[13] = {wq,wk,wv,wo,ega_wg,g1_w1,g1_w2,g1_wg,cla_w1,cla_w2,g2_w1,g2_w2,g2_wg};
    u16* Wdst[13] = {wqT,wkT,wvT,woT,egaT,g1w1T,g1w2T,g1wgT,claw1T,claw2T,g2w1T,g2w2T,g2wgT};
    int Ks[13] = {512,512,512,512,512, 512,1536,512, 512,512, 512,1536,512};
    int Ns[13] = {512,512,512,512,512, 3072,512,512, 1024,512, 3072,512,512};
    int off = 0;
    for(int t=0;t<13;t++){
      J.W[t]=Wsrc[t]; J.WT[t]=Wdst[t]; J.K[t]=Ks[t]; J.N[t]=Ns[t];
      J.off[t]=off; off += (Ns[t]>>5)*(Ks[t]>>5);
    }
    J.off[13]=off;
    k_wt_all<<<off, blk, 0, stream>>>(J);
  }
  k_cat3<<<6, blk, 0, stream>>>(bq, bk, bv, bias_qkv);

  // ================= EGA =================
  k_poolcastln<<<rowsP, 64, 0, stream>>>(x, xbA, lnPb, mha_g, mha_b);
  k_gemm_mfma<0,2><<<gQKV, blk, 0, stream>>>(lnPb, WTb, bias_qkv, nullptr,nullptr, nullptr, qkv, rowsP, NQKV, ND);
  k_qkt_mfma<<<dim3(4,4,64), blk, 0, stream>>>(qkv, SCb);
  k_bmsm_mfma<<<512, 256, 0, stream>>>(SCb, qkv, pos, Pb);
  k_pv_mfma<<<dim3(8,64), blk, 0, stream>>>(Pb, qkv, s5b);
  k_gemm_mfma<0,1><<<gPool1, blk, 0, stream>>>(s5b, woT, bo, nullptr,nullptr, nullptr, s6b, rowsP, ND, ND);
  k_gemm_mfma<1,2><<<gFull2, blk, 0, stream>>>(xbA, egaT, ega_bg, xbA, s6b, nullptr, xbB, rowsF, ND, ND);

  // ================= GCFN global (g1) =================
  k_poollnb<<<rowsP, 64, 0, stream>>>(xbB, lnPb, g1_ln_g, g1_ln_b);
  k_glu_mfma<<<dim3(24,32), blk, 0, stream>>>(lnPb, g1w1T, g1_b1, glu_p, rowsP, 1536, ND);
  k_gemm_mfma<0,1><<<gPool1, blk, 0, stream>>>(glu_p, g1w2T, g1_b2, nullptr,nullptr, nullptr, s6b, rowsP, ND, 1536);
  k_gemm_mfma<1,2><<<gFull2, blk, 0, stream>>>(xbB, g1wgT, g1_bg, xbB, s6b, nullptr, xbA, rowsF, ND, ND);

  // ================= CLA =================
  k_lnb4<<<rowsF/4, blk, 0, stream>>>(xbA, lnFb, cla_ln_g, cla_ln_b);
  k_glu_mfma<<<dim3(8,128), blk, 0, stream>>>(lnFb, claw1T, cla_b1, glu_b, rowsF, 512, ND);
  k_dwconv<<<dim3(8, NT/64, NB), blk, 0, stream>>>(glu_b, dw_w, dw_b, conv_b);
  k_gemm_mfma<2,2><<<gFull2, blk, 0, stream>>>(conv_b, claw2T, cla_b2, xbA, nullptr, nullptr, xbB, rowsF, ND, ND);

  // ================= GCFN local (g2) =================
  k_poollnb<<<rowsP, 64, 0, stream>>>(xbB, lnPb, g2_ln_g, g2_ln_b);
  k_glu_mfma<<<dim3(24,32), blk, 0, stream>>>(lnPb, g2w1T, g2_b1, glu_p, rowsP, 1536, ND);
  k_gemm_mfma<0,1><<<gPool1, blk, 0, stream>>>(glu_p, g2w2T, g2_b2, nullptr,nullptr, nullptr, s6b, rowsP, ND, 1536);
  k_gemm_mfma<1,2><<<gFull2, blk, 0, stream>>>(xbB, g2wgT, g2_bg, xbB, s6b, xo, nullptr, rowsF, ND, ND);
}

// Round 24
// 332.049 us; speedup vs baseline: 1.0043x; 1.0043x over previous
//
#include <hip/hip_runtime.h>
#include <math.h>

#define NB 8
#define NT 2048
#define ND 512
#define NH 8
#define NDK 64
#define NL 512
#define NQKV 1536

typedef unsigned short u16;
typedef __attribute__((ext_vector_type(8))) short bf16x8;
typedef __attribute__((ext_vector_type(4))) float f32x4;

__device__ __forceinline__ float sigf(float v){ return 1.0f/(1.0f+__expf(-v)); }

__device__ __forceinline__ u16 f2b(float f){
  union{float f; unsigned u;} v; v.f = f;
  unsigned r = v.u + 0x7fffu + ((v.u>>16)&1u);
  return (u16)(r>>16);
}
__device__ __forceinline__ float b2f(u16 h){
  union{unsigned u; float f;} v; v.u = ((unsigned)h)<<16; return v.f;
}

#define GLOAD16(src, dst) \
  __builtin_amdgcn_global_load_lds((const __attribute__((address_space(1))) void*)(src), \
                                   (__attribute__((address_space(3))) void*)(dst), 16, 0, 0)

// ---------------- fused pool4 + LayerNorm + bf16 stream copy, f32 in ----------------
__global__ void k_poolcastln(const float* __restrict__ in, u16* __restrict__ xb,
                             u16* __restrict__ outb,
                             const float* __restrict__ gam, const float* __restrict__ bet){
  size_t prow = blockIdx.x;
  int lane = threadIdx.x;   // 64
  const float* p = in + prow*4*ND + lane*8;
  float x[8] = {0,0,0,0,0,0,0,0};
  #pragma unroll
  for(int rr=0;rr<4;rr++){
    float4 a = *(const float4*)&p[(size_t)rr*ND];
    float4 b = *(const float4*)&p[(size_t)rr*ND+4];
    uint4 pk;
    pk.x = (unsigned)f2b(a.x) | ((unsigned)f2b(a.y)<<16);
    pk.y = (unsigned)f2b(a.z) | ((unsigned)f2b(a.w)<<16);
    pk.z = (unsigned)f2b(b.x) | ((unsigned)f2b(b.y)<<16);
    pk.w = (unsigned)f2b(b.z) | ((unsigned)f2b(b.w)<<16);
    *(uint4*)&xb[(prow*4+rr)*ND + lane*8] = pk;
    x[0]+=a.x; x[1]+=a.y; x[2]+=a.z; x[3]+=a.w;
    x[4]+=b.x; x[5]+=b.y; x[6]+=b.z; x[7]+=b.w;
  }
  #pragma unroll
  for(int e=0;e<8;e++) x[e]*=0.25f;
  float s=0.f, ss=0.f;
  #pragma unroll
  for(int e=0;e<8;e++){ s+=x[e]; ss+=x[e]*x[e]; }
  #pragma unroll
  for(int o=32;o;o>>=1){ s+=__shfl_xor(s,o); ss+=__shfl_xor(ss,o); }
  float m  = s*(1.0f/ND);
  float rs = rsqrtf(ss*(1.0f/ND)-m*m+1e-5f);
  const float4* gp=(const float4*)gam; const float4* bp=(const float4*)bet;
  float4 g0=gp[lane*2],g1=gp[lane*2+1],b0=bp[lane*2],b1=bp[lane*2+1];
  float o0=(x[0]-m)*rs*g0.x+b0.x, o1=(x[1]-m)*rs*g0.y+b0.y;
  float o2=(x[2]-m)*rs*g0.z+b0.z, o3=(x[3]-m)*rs*g0.w+b0.w;
  float o4=(x[4]-m)*rs*g1.x+b1.x, o5=(x[5]-m)*rs*g1.y+b1.y;
  float o6=(x[6]-m)*rs*g1.z+b1.z, o7=(x[7]-m)*rs*g1.w+b1.w;
  uint4 pk;
  pk.x = (unsigned)f2b(o0) | ((unsigned)f2b(o1)<<16);
  pk.y = (unsigned)f2b(o2) | ((unsigned)f2b(o3)<<16);
  pk.z = (unsigned)f2b(o4) | ((unsigned)f2b(o5)<<16);
  pk.w = (unsigned)f2b(o6) | ((unsigned)f2b(o7)<<16);
  *(uint4*)&outb[prow*ND + lane*8] = pk;
}

// ---------------- row LayerNorm, bf16 in -> bf16 out, 4 rows/block ----------------
__global__ __launch_bounds__(256)
void k_lnb4(const u16* __restrict__ in, u16* __restrict__ outb,
            const float* __restrict__ gam, const float* __restrict__ bet){
  size_t row = (size_t)blockIdx.x*4 + (threadIdx.x>>6);
  int lane = threadIdx.x & 63;
  const u16* p = in + row*ND + lane*8;
  ushort4 a0 = *(const ushort4*)p;
  ushort4 a1 = *(const ushort4*)(p+4);
  float x0=b2f(a0.x),x1=b2f(a0.y),x2=b2f(a0.z),x3=b2f(a0.w);
  float x4=b2f(a1.x),x5=b2f(a1.y),x6=b2f(a1.z),x7=b2f(a1.w);
  float s  = x0+x1+x2+x3+x4+x5+x6+x7;
  float ss = x0*x0+x1*x1+x2*x2+x3*x3+x4*x4+x5*x5+x6*x6+x7*x7;
  #pragma unroll
  for(int o=32;o;o>>=1){ s+=__shfl_xor(s,o); ss+=__shfl_xor(ss,o); }
  float m  = s*(1.0f/ND);
  float rs = rsqrtf(ss*(1.0f/ND)-m*m+1e-5f);
  const float4* gp=(const float4*)gam; const float4* bp=(const float4*)bet;
  float4 g0=gp[lane*2],g1=gp[lane*2+1],b0=bp[lane*2],b1=bp[lane*2+1];
  float o0=(x0-m)*rs*g0.x+b0.x, o1=(x1-m)*rs*g0.y+b0.y;
  float o2=(x2-m)*rs*g0.z+b0.z, o3=(x3-m)*rs*g0.w+b0.w;
  float o4=(x4-m)*rs*g1.x+b1.x, o5=(x5-m)*rs*g1.y+b1.y;
  float o6=(x6-m)*rs*g1.z+b1.z, o7=(x7-m)*rs*g1.w+b1.w;
  uint4 pk;
  pk.x = (unsigned)f2b(o0) | ((unsigned)f2b(o1)<<16);
  pk.y = (unsigned)f2b(o2) | ((unsigned)f2b(o3)<<16);
  pk.z = (unsigned)f2b(o4) | ((unsigned)f2b(o5)<<16);
  pk.w = (unsigned)f2b(o6) | ((unsigned)f2b(o7)<<16);
  *(uint4*)&outb[row*ND + lane*8] = pk;
}

// ---------------- bias concat: [bq|bk|bv] -> 1536 f32 ----------------
__global__ void k_cat3(const float* __restrict__ a, const float* __restrict__ b,
                       const float* __restrict__ c, float* __restrict__ o){
  int t = blockIdx.x*256 + threadIdx.x;
  if(t >= 1536) return;
  o[t] = t < 512 ? a[t] : (t < 1024 ? b[t-512] : c[t-1024]);
}

// ---------------- merged weight transpose+cast: 13 jobs, one launch ----------------
struct WtJobs {
  const float* W[13];
  u16* WT[13];
  int K[13], N[13];
  int off[14];
};
__global__ __launch_bounds__(256)
void k_wt_all(WtJobs jobs){
  __shared__ float ls[32][33];
  int bid = blockIdx.x;
  int ji = 0;
  #pragma unroll
  for(int t=0;t<12;t++) if(bid >= jobs.off[t+1]) ji = t+1;
  int local = bid - jobs.off[ji];
  const float* W = jobs.W[ji];
  u16* WT = jobs.WT[ji];
  int K = jobs.K[ji], N = jobs.N[ji];
  int tn = N>>5;
  int n0 = (local % tn)*32, k0 = (local / tn)*32;
  int tid = threadIdx.x;
  int tx = tid&31, ty = tid>>5;
  #pragma unroll
  for(int p=0;p<4;p++)
    ls[ty+p*8][tx] = W[(size_t)(k0+ty+p*8)*N + n0+tx];
  __syncthreads();
  #pragma unroll
  for(int p=0;p<4;p++)
    WT[(size_t)(n0+ty+p*8)*K + k0+tx] = f2b(ls[tx][ty+p*8]);
}

// =======================================================================
// MFMA GEMM (generic): C = A_bf16[M,K] @ BT_bf16[N,K]^T (+ epilogue)
// BK=64, 128B LDS rows with 8-chunk XOR involution (chunk c at c^(row&7)).
// MI in {1,2,4} -> BM = 32/64/128.
// R24: optional fused 4:1 pool output (poolB) — each thread's 4 r-values
// for fixed (i,j) are one pool group (r0 multiple of 4, gr 4-aligned).
// =======================================================================
template<int EPI, int MI>
__global__ __launch_bounds__(256, 3)
void k_gemm_mfma(const u16* __restrict__ A, const u16* __restrict__ BT,
                 const float* __restrict__ bias,
                 const u16* __restrict__ xinB, const u16* __restrict__ upB,
                 float* __restrict__ outF, u16* __restrict__ outB,
                 u16* __restrict__ poolB,
                 int M, int N, int K){
  constexpr int BM = MI*32;
  __shared__ short lA[BM*64];
  __shared__ short lB[128*64];
  int tid = threadIdx.x;
  int wv_ = tid>>6, ln_ = tid&63;
  int wy = wv_>>1, wx = wv_&1;
  int nx = gridDim.x;
  int flat = blockIdx.y*nx + blockIdx.x;
  int cpx = (nx*gridDim.y)>>3;
  int swz = (flat&7)*cpx + (flat>>3);
  int m0 = (swz/nx)*BM, n0 = (swz%nx)*128;

  f32x4 acc[MI][4];
  #pragma unroll
  for(int i=0;i<MI;i++)
    #pragma unroll
    for(int j=0;j<4;j++){ f32x4 z = {0.f,0.f,0.f,0.f}; acc[i][j]=z; }

  int fr = ln_&15, kg = ln_>>4;

  for(int k0=0;k0<K;k0+=64){
    #pragma unroll
    for(int q=0;q<MI;q++){
      int s = q*256 + tid;
      int row = s>>3;
      int gl = (s&7) ^ (row&7);
      GLOAD16(A + (size_t)(m0+row)*K + k0 + gl*8, &lA[s*8]);
    }
    #pragma unroll
    for(int q=0;q<4;q++){
      int s = q*256 + tid;
      int row = s>>3;
      int gl = (s&7) ^ (row&7);
      GLOAD16(BT + (size_t)(n0+row)*K + k0 + gl*8, &lB[s*8]);
    }
    __syncthreads();
    #pragma unroll
    for(int kk=0;kk<2;kk++){
      bf16x8 af[MI], bf[4];
      #pragma unroll
      for(int i=0;i<MI;i++){
        int ar = wy*(MI*16) + i*16 + fr;
        af[i] = *(const bf16x8*)((const char*)lA + ar*128 + (((kk*4+kg) ^ (ar&7))<<4));
      }
      #pragma unroll
      for(int j=0;j<4;j++){
        int br = wx*64 + j*16 + fr;
        bf[j] = *(const bf16x8*)((const char*)lB + br*128 + (((kk*4+kg) ^ (br&7))<<4));
      }
      #pragma unroll
      for(int i=0;i<MI;i++)
        #pragma unroll
        for(int j=0;j<4;j++)
          acc[i][j] = __builtin_amdgcn_mfma_f32_16x16x32_bf16(af[i], bf[j], acc[i][j], 0,0,0);
    }
    __syncthreads();
  }

  int r0 = (ln_>>4)*4, c0 = ln_&15;
  #pragma unroll
  for(int i=0;i<MI;i++){
    #pragma unroll
    for(int j=0;j<4;j++){
      int gr = m0 + wy*(MI*16) + i*16 + r0;   // 4-aligned
      int gc = n0 + wx*64 + j*16 + c0;
      float bv = bias[gc];
      float psum = 0.f;
      #pragma unroll
      for(int r=0;r<4;r++){
        float val = acc[i][j][r] + bv;
        size_t idx = (size_t)(gr+r)*N + gc;
        float o;
        if(EPI==0){
          o = val;
        } else if(EPI==1){
          o = b2f(xinB[idx]) + sigf(val)*b2f(upB[(size_t)((gr+r)>>2)*N + gc]);
        } else {
          o = b2f(xinB[idx]) + val;
        }
        psum += o;
        if(outF) outF[idx] = o;
        if(outB) outB[idx] = f2b(o);
      }
      if(poolB) poolB[(size_t)(gr>>2)*N + gc] = f2b(psum*0.25f);
    }
  }
}

// =======================================================================
// MFMA GLU GEMM — BK=64
// =======================================================================
__global__ __launch_bounds__(256, 3)
void k_glu_mfma(const u16* __restrict__ A, const u16* __restrict__ WT,
                const float* __restrict__ bias, u16* __restrict__ outB,
                int M, int Dh, int K){
  __shared__ short lA [128*64];
  __shared__ short lBa[64*64];
  __shared__ short lBb[64*64];
  int tid = threadIdx.x;
  int wv_ = tid>>6, ln_ = tid&63;
  int wy = wv_>>1, wx = wv_&1;
  int nx = gridDim.x;
  int flat = blockIdx.y*nx + blockIdx.x;
  int cpx = (nx*gridDim.y)>>3;
  int swz = (flat&7)*cpx + (flat>>3);
  int m0 = (swz/nx)*128, n0 = (swz%nx)*64;

  f32x4 aca[4][2], acb[4][2];
  #pragma unroll
  for(int i=0;i<4;i++)
    #pragma unroll
    for(int j=0;j<2;j++){ f32x4 z={0.f,0.f,0.f,0.f}; aca[i][j]=z; acb[i][j]=z; }

  int fr = ln_&15, kg = ln_>>4;

  for(int k0=0;k0<K;k0+=64){
    #pragma unroll
    for(int q=0;q<4;q++){
      int s = q*256 + tid;
      int row = s>>3;
      int gl = (s&7) ^ (row&7);
      GLOAD16(A + (size_t)(m0+row)*K + k0 + gl*8, &lA[s*8]);
    }
    #pragma unroll
    for(int q=0;q<2;q++){
      int s = q*256 + tid;
      int row = s>>3;
      int gl = (s&7) ^ (row&7);
      GLOAD16(WT + (size_t)(n0+row)*K    + k0 + gl*8, &lBa[s*8]);
      GLOAD16(WT + (size_t)(Dh+n0+row)*K + k0 + gl*8, &lBb[s*8]);
    }
    __syncthreads();
    #pragma unroll
    for(int kk=0;kk<2;kk++){
      bf16x8 af[4], ba[2], bb[2];
      #pragma unroll
      for(int i=0;i<4;i++){
        int ar = wy*64 + i*16 + fr;
        af[i] = *(const bf16x8*)((const char*)lA + ar*128 + (((kk*4+kg) ^ (ar&7))<<4));
      }
      #pragma unroll
      for(int j=0;j<2;j++){
        int br = wx*32 + j*16 + fr;
        int off = br*128 + (((kk*4+kg) ^ (br&7))<<4);
        ba[j] = *(const bf16x8*)((const char*)lBa + off);
        bb[j] = *(const bf16x8*)((const char*)lBb + off);
      }
      #pragma unroll
      for(int i=0;i<4;i++)
        #pragma unroll
        for(int j=0;j<2;j++){
          aca[i][j] = __builtin_amdgcn_mfma_f32_16x16x32_bf16(af[i], ba[j], aca[i][j], 0,0,0);
          acb[i][j] = __builtin_amdgcn_mfma_f32_16x16x32_bf16(af[i], bb[j], acb[i][j], 0,0,0);
        }
    }
    __syncthreads();
  }

  int r0 = (ln_>>4)*4, c0 = ln_&15;
  #pragma unroll
  for(int i=0;i<4;i++){
    #pragma unroll
    for(int j=0;j<2;j++){
      int gr = m0 + wy*64 + i*16 + r0;
      int gc = n0 + wx*32 + j*16 + c0;
      float bva = bias[gc], bvb = bias[Dh+gc];
      #pragma unroll
      for(int r=0;r<4;r++){
        float o = (aca[i][j][r]+bva) * sigf(acb[i][j][r]+bvb);
        outB[(size_t)(gr+r)*Dh + gc] = f2b(o);
      }
    }
  }
}

// =======================================================================
// MFMA QK^T — single BK=64 step. q/k from fused qkv [row][1536].
// =======================================================================
__global__ __launch_bounds__(256, 3)
void k_qkt_mfma(const u16* __restrict__ qkv, u16* __restrict__ SC){
  int z = blockIdx.z, b = z>>3, h = z&7;
  int i0 = blockIdx.y*128, j0 = blockIdx.x*128;
  __shared__ short lA[128*64];
  __shared__ short lB[128*64];
  int tid = threadIdx.x;
  int wv_ = tid>>6, ln_ = tid&63;
  int wy = wv_>>1, wx = wv_&1;
  const u16* Ab = qkv + ((size_t)b*NL + i0)*NQKV + h*NDK;
  const u16* Bb = qkv + ((size_t)b*NL + j0)*NQKV + 512 + h*NDK;

  f32x4 acc[4][4];
  #pragma unroll
  for(int i=0;i<4;i++)
    #pragma unroll
    for(int j=0;j<4;j++){ f32x4 zz={0.f,0.f,0.f,0.f}; acc[i][j]=zz; }

  int fr = ln_&15, kg = ln_>>4;

  #pragma unroll
  for(int q=0;q<4;q++){
    int s = q*256 + tid;
    int row = s>>3;
    int gl = (s&7) ^ (row&7);
    GLOAD16(Ab + (size_t)row*NQKV + gl*8, &lA[s*8]);
    GLOAD16(Bb + (size_t)row*NQKV + gl*8, &lB[s*8]);
  }
  __syncthreads();
  #pragma unroll
  for(int kk=0;kk<2;kk++){
    bf16x8 af[4], bf[4];
    #pragma unroll
    for(int i=0;i<4;i++){
      int ar = wy*64 + i*16 + fr;
      af[i] = *(const bf16x8*)((const char*)lA + ar*128 + (((kk*4+kg) ^ (ar&7))<<4));
    }
    #pragma unroll
    for(int j=0;j<4;j++){
      int br = wx*64 + j*16 + fr;
      bf[j] = *(const bf16x8*)((const char*)lB + br*128 + (((kk*4+kg) ^ (br&7))<<4));
    }
    #pragma unroll
    for(int i=0;i<4;i++)
      #pragma unroll
      for(int j=0;j<4;j++)
        acc[i][j] = __builtin_amdgcn_mfma_f32_16x16x32_bf16(af[i], bf[j], acc[i][j], 0,0,0);
  }

  u16* sb = SC + (size_t)z*NL*NL;
  int r0 = (ln_>>4)*4, c0 = ln_&15;
  #pragma unroll
  for(int i=0;i<4;i++){
    #pragma unroll
    for(int j=0;j<4;j++){
      int gr = i0 + wy*64 + i*16 + r0;
      int gc = j0 + wx*64 + j*16 + c0;
      #pragma unroll
      for(int r=0;r<4;r++)
        sb[(size_t)(gr+r)*NL + gc] = f2b(acc[i][j][r]);
    }
  }
}

// =======================================================================
// MFMA Bm + softmax — R22 form (restored; R23 LDS-seed variant was neutral
// with doubled bank conflicts). q from fused qkv (stride 1536).
// =======================================================================
__global__ __launch_bounds__(256, 2)
void k_bmsm_mfma(const u16* __restrict__ SC, const u16* __restrict__ qkv,
                 const float* __restrict__ pos, u16* __restrict__ P){
  int i = blockIdx.x;
  __shared__ u16 posB[512*64];   // 64 KB bf16, chunk-swizzled; reused as P repack
  int tid = threadIdx.x;
  int w = tid>>6, ln = tid&63;
  int fr = ln&15, kg = ln>>4;
  const float* pp = pos + (size_t)i*NL*NDK;

  #pragma unroll
  for(int rr=0;rr<2;rr++){
    int j = rr*256 + tid;
    const float* rp = pp + (size_t)j*64;
    #pragma unroll
    for(int c=0;c<8;c++){
      float4 a = *(const float4*)&rp[c*8];
      float4 b = *(const float4*)&rp[c*8+4];
      uint4 pk;
      pk.x = (unsigned)f2b(a.x) | ((unsigned)f2b(a.y)<<16);
      pk.y = (unsigned)f2b(a.z) | ((unsigned)f2b(a.w)<<16);
      pk.z = (unsigned)f2b(b.x) | ((unsigned)f2b(b.y)<<16);
      pk.w = (unsigned)f2b(b.z) | ((unsigned)f2b(b.w)<<16);
      int cw = c ^ (j&7);
      *(uint4*)((char*)posB + j*128 + cw*16) = pk;
    }
  }
  bf16x8 af[2];
  #pragma unroll
  for(int kk=0;kk<2;kk++){
    int bh = w*16 + fr;
    af[kk] = *(const bf16x8*)(qkv + ((size_t)(bh>>3)*NL + i)*NQKV + (bh&7)*NDK + kk*32 + kg*8);
  }
  f32x4 acc[2][16];
  #pragma unroll
  for(int H=0;H<2;H++)
    #pragma unroll
    for(int r=0;r<4;r++){
      int bh = w*16 + kg*4 + r;
      const u16* scr = SC + ((size_t)bh*NL + i)*NL + H*256 + fr;
      #pragma unroll
      for(int nj=0;nj<16;nj++)
        acc[H][nj][r] = b2f(scr[nj*16]);
    }
  __syncthreads();

  #pragma unroll
  for(int H=0;H<2;H++)
    #pragma unroll
    for(int nj=0;nj<16;nj++){
      int j = H*256 + nj*16 + fr;
      #pragma unroll
      for(int kk=0;kk<2;kk++){
        int cw = (kk*4 + kg) ^ (j&7);
        bf16x8 bfrag = *(const bf16x8*)((const char*)posB + j*128 + (cw<<4));
        acc[H][nj] = __builtin_amdgcn_mfma_f32_16x16x32_bf16(af[kk], bfrag, acc[H][nj], 0,0,0);
      }
    }

  float inv_[4];
  #pragma unroll
  for(int r=0;r<4;r++){
    float m = -3e38f;
    #pragma unroll
    for(int H=0;H<2;H++)
      #pragma unroll
      for(int nj=0;nj<16;nj++){
        acc[H][nj][r] *= 0.125f;
        m = fmaxf(m, acc[H][nj][r]);
      }
    #pragma unroll
    for(int o=8;o;o>>=1) m = fmaxf(m, __shfl_xor(m,o));
    float s = 0.f;
    #pragma unroll
    for(int H=0;H<2;H++)
      #pragma unroll
      for(int nj=0;nj<16;nj++){
        acc[H][nj][r] = __expf(acc[H][nj][r] - m);
        s += acc[H][nj][r];
      }
    #pragma unroll
    for(int o=8;o;o>>=1) s += __shfl_xor(s,o);
    inv_[r] = 1.0f/s;
  }

  __syncthreads();
  u16* Pls = posB;
  #pragma unroll
  for(int r=0;r<4;r++){
    int bh = w*16 + kg*4 + r;
    #pragma unroll
    for(int H=0;H<2;H++)
      #pragma unroll
      for(int nj=0;nj<16;nj++)
        Pls[bh*512 + H*256 + nj*16 + fr] = f2b(acc[H][nj][r]*inv_[r]);
  }
  __syncthreads();
  #pragma unroll
  for(int t0=0;t0<16;t0++){
    int t = t0*256 + tid;
    int bh = t>>6, j8 = (t&63)*8;
    uint4 v = *(const uint4*)&Pls[bh*512 + j8];
    *(uint4*)&P[((size_t)bh*NL + i)*NL + j8] = v;
  }
}

// =======================================================================
// MFMA PV — BM=64; v from fused qkv
// =======================================================================
__global__ __launch_bounds__(256, 3)
void k_pv_mfma(const u16* __restrict__ P, const u16* __restrict__ qkv,
               u16* __restrict__ o){
  int z = blockIdx.y, b = z>>3, h = z&7;
  int i0 = blockIdx.x*64;
  __shared__ short lA[64*32];
  __shared__ short lBt[64*64];
  int tid = threadIdx.x;
  int wv_ = tid>>6, ln_ = tid&63;
  int wy = wv_>>1, wx = wv_&1;
  const u16* Ab = P + ((size_t)z*NL + i0)*NL;
  const u16* vb = qkv + (size_t)b*NL*NQKV + 1024 + h*NDK;   // v

  f32x4 acc[2][2];
  #pragma unroll
  for(int mi=0;mi<2;mi++)
    #pragma unroll
    for(int nj=0;nj<2;nj++){ f32x4 zz={0.f,0.f,0.f,0.f}; acc[mi][nj]=zz; }

  int fr = ln_&15, kg = ln_>>4;
  int aoff[2];
  #pragma unroll
  for(int mi=0;mi<2;mi++){
    int ar = wy*32 + mi*16 + fr;
    aoff[mi] = ar*64 + ((kg ^ ((ar>>1)&3))<<4);
  }
  int boff[2];
  #pragma unroll
  for(int nj=0;nj<2;nj++){
    int n = wx*32 + nj*16 + fr;
    boff[nj] = (n*128 + kg*16) ^ ((n&7)<<4);
  }
  int jrow = tid>>3, d8 = (tid&7)*8;

  for(int k0=0;k0<NL;k0+=32){
    {
      int s = tid;
      int row = s>>2;
      int gl = (s&3) ^ ((row>>1)&3);
      GLOAD16(Ab + (size_t)row*NL + k0 + gl*8, &lA[wv_*512]);
    }
    {
      uint4 v = *(const uint4*)&vb[(size_t)(k0 + jrow)*NQKV + d8];
      u16 e[8];
      e[0]=(u16)(v.x&0xffff); e[1]=(u16)(v.x>>16);
      e[2]=(u16)(v.y&0xffff); e[3]=(u16)(v.y>>16);
      e[4]=(u16)(v.z&0xffff); e[5]=(u16)(v.z>>16);
      e[6]=(u16)(v.w&0xffff); e[7]=(u16)(v.w>>16);
      #pragma unroll
      for(int ee=0;ee<8;ee++){
        int d = d8+ee;
        int byt = (d*128 + jrow*2) ^ ((d&7)<<4);
        *(u16*)((char*)lBt + byt) = e[ee];
      }
    }
    __syncthreads();
    bf16x8 af[2], bf[2];
    #pragma unroll
    for(int mi=0;mi<2;mi++) af[mi] = *(const bf16x8*)((const char*)lA + aoff[mi]);
    #pragma unroll
    for(int nj=0;nj<2;nj++) bf[nj] = *(const bf16x8*)((const char*)lBt + boff[nj]);
    #pragma unroll
    for(int mi=0;mi<2;mi++)
      #pragma unroll
      for(int nj=0;nj<2;nj++)
        acc[mi][nj] = __builtin_amdgcn_mfma_f32_16x16x32_bf16(af[mi], bf[nj], acc[mi][nj], 0,0,0);
    __syncthreads();
  }

  int r0 = (ln_>>4)*4;
  #pragma unroll
  for(int mi=0;mi<2;mi++){
    #pragma unroll
    for(int nj=0;nj<2;nj++){
      #pragma unroll
      for(int r=0;r<4;r++){
        int gi = i0 + wy*32 + mi*16 + r0 + r;
        int gd = wx*32 + nj*16 + fr;
        o[((size_t)b*NL + gi)*ND + h*NDK + gd] = f2b(acc[mi][nj][r]);
      }
    }
  }
}

// =======================================================================
// depthwise conv1d, K=31, SAME — LDS-tiled (R17/R22 verified form)
// =======================================================================
__global__ __launch_bounds__(256, 2)
void k_dwconv(const u16* __restrict__ in, const float* __restrict__ w,
              const float* __restrict__ bias, u16* __restrict__ out){
  __shared__ u16 tile[94][64];
  int c0 = blockIdx.x*64;
  int t0 = blockIdx.y*64;
  int b  = blockIdx.z;
  int tid = threadIdx.x;
  const u16* ib = in + (size_t)b*NT*ND + c0;
  for(int s = tid; s < 94*16; s += 256){
    int r  = s >> 4;
    int cc = (s & 15) * 4;
    int t  = t0 - 15 + r;
    uint2 v = make_uint2(0u, 0u);
    if(t >= 0 && t < NT) v = *(const uint2*)&ib[(size_t)t*ND + cc];
    *(uint2*)&tile[r][cc] = v;
  }
  __syncthreads();
  int c  = tid & 63;
  int tg = tid >> 6;
  float wg[31];
  #pragma unroll
  for(int kk=0;kk<31;kk++) wg[kk] = w[(c0+c)*31+kk];
  float bs = bias[c0+c];
  float win[46];
  #pragma unroll
  for(int r=0;r<46;r++) win[r] = b2f(tile[tg*16 + r][c]);
  u16* ob = out + (size_t)b*NT*ND + (size_t)(t0 + tg*16)*ND + c0 + c;
  #pragma unroll
  for(int oo=0;oo<16;oo++){
    float s = bs;
    #pragma unroll
    for(int kk=0;kk<31;kk++) s += win[oo+kk]*wg[kk];
    ob[(size_t)oo*ND] = f2b(s);
  }
}

extern "C" void kernel_launch(void* const* d_in, const int* in_sizes, int n_in,
                              void* d_out, int out_size, void* d_ws, size_t ws_size,
                              hipStream_t stream) {
  const float* x      = (const float*)d_in[0];
  const float* pos    = (const float*)d_in[1];
  const float* mha_g  = (const float*)d_in[2];
  const float* mha_b  = (const float*)d_in[3];
  const float* wq     = (const float*)d_in[4];
  const float* bq     = (const float*)d_in[5];
  const float* wk     = (const float*)d_in[6];
  const float* bk     = (const float*)d_in[7];
  const float* wv     = (const float*)d_in[8];
  const float* bv     = (const float*)d_in[9];
  const float* wo     = (const float*)d_in[10];
  const float* bo     = (const float*)d_in[11];
  const float* ega_wg = (const float*)d_in[12];
  const float* ega_bg = (const float*)d_in[13];
  const float* g1_ln_g= (const float*)d_in[14];
  const float* g1_ln_b= (const float*)d_in[15];
  const float* g1_w1  = (const float*)d_in[16];
  const float* g1_b1  = (const float*)d_in[17];
  const float* g1_w2  = (const float*)d_in[18];
  const float* g1_b2  = (const float*)d_in[19];
  const float* g1_wg  = (const float*)d_in[20];
  const float* g1_bg  = (const float*)d_in[21];
  const float* cla_ln_g=(const float*)d_in[22];
  const float* cla_ln_b=(const float*)d_in[23];
  const float* cla_w1 = (const float*)d_in[24];
  const float* cla_b1 = (const float*)d_in[25];
  const float* dw_w   = (const float*)d_in[26];
  const float* dw_b   = (const float*)d_in[27];
  const float* cla_w2 = (const float*)d_in[28];
  const float* cla_b2 = (const float*)d_in[29];
  const float* g2_ln_g= (const float*)d_in[30];
  const float* g2_ln_b= (const float*)d_in[31];
  const float* g2_w1  = (const float*)d_in[32];
  const float* g2_b1  = (const float*)d_in[33];
  const float* g2_w2  = (const float*)d_in[34];
  const float* g2_b2  = (const float*)d_in[35];
  const float* g2_wg  = (const float*)d_in[36];
  const float* g2_bg  = (const float*)d_in[37];

  float* xo = (float*)d_out;
  float* ws = (float*)d_ws;
  const size_t M1 = 1024*1024;

  u16*  SCb    = (u16*)ws;                 // scores bf16 [0,8M) (attn phase)
  u16*  s5b    = (u16*)ws;                 // [0,1)   attn out bf16
  u16*  poolRaw= (u16*)ws;                 // [0,1)   fused pool4 out (gate/add epilogue)
  u16*  glu_p  = (u16*)ws;                 // [0,6)   g1/g2 GLU out
  u16*  glu_b  = (u16*)ws;                 // [0,4)   CLA GLU out
  u16*  conv_b = (u16*)(ws + 4*M1);        // [4,8)   CLA conv out
  u16*  s6b    = (u16*)(ws + 6*M1);        // [6,7)   'up' bf16
  u16*  lnPb   = (u16*)(ws + 7*M1);        // [7,8)   pooled ln bf16
  u16*  lnFb   = (u16*)(ws + 8*M1);        // [8,12)  CLA ln bf16
  u16*  Pb     = (u16*)(ws + 16*M1);       // [16,24) attn probs bf16
  u16*  xbA    = (u16*)(ws + 24*M1);       // [24,28) stream ping
  u16*  xbB    = (u16*)(ws + 28*M1);       // [28,32) stream pong
  u16*  WTb    = (u16*)(ws + 32*M1);       // [32,36) bf16 weights
  u16*  qkv    = (u16*)(ws + 38*M1);       // [38,41) fused qkv bf16 [4096][1536]
  float* bias_qkv = ws + 41*M1;            // 1536 f32

  u16* wqT   = WTb + 0;
  u16* wkT   = WTb + 262144;
  u16* wvT   = WTb + 524288;
  u16* woT   = WTb + 786432;
  u16* egaT  = WTb + 1048576;
  u16* g1w1T = WTb + 1310720;
  u16* g1w2T = WTb + 2883584;
  u16* g1wgT = WTb + 3670016;
  u16* claw1T= WTb + 3932160;
  u16* claw2T= WTb + 4456448;
  u16* g2w1T = WTb + 4718592;
  u16* g2w2T = WTb + 6291456;
  u16* g2wgT = WTb + 7077888;

  const int rowsP = NB*NL;        // 4096
  const int rowsF = NB*NT;        // 16384
  dim3 blk(256);
  dim3 gPool1(4,128);             // pooled GEMM (N=512): BM=32 -> 512 blocks, 2/CU
  dim3 gQKV(12,64);               // pooled GEMM (N=1536): BM=64 -> 768 blocks
  dim3 gFull2(4,256);             // full-T GEMM: BM=64 -> 1024 blocks

  // ---- weight prep ----
  {
    WtJobs J;
    const float* Wsrc[13] = {wq,wk,wv,wo,ega_wg,g1_w1,g1_w2,g1_wg,cla_w1,cla_w2,g2_w1,g2_w2,g2_wg};
    u16* Wdst[13] = {wqT,wkT,wvT,woT,egaT,g1w1T,g1w2T,g1wgT,claw1T,claw2T,g2w1T,g2w2T,g2wgT};
    int Ks[13] = {512,512,512,512,512, 512,1536,512, 512,512, 512,1536,512};
    int Ns[13] = {512,512,512,512,512, 3072,512,512, 1024,512, 3072,512,512};
    int off = 0;
    for(int t=0;t<13;t++){
      J.W[t]=Wsrc[t]; J.WT[t]=Wdst[t]; J.K[t]=Ks[t]; J.N[t]=Ns[t];
      J.off[t]=off; off += (Ns[t]>>5)*(Ks[t]>>5);
    }
    J.off[13]=off;
    k_wt_all<<<off, blk, 0, stream>>>(J);
  }
  k_cat3<<<6, blk, 0, stream>>>(bq, bk, bv, bias_qkv);

  // ================= EGA =================
  k_poolcastln<<<rowsP, 64, 0, stream>>>(x, xbA, lnPb, mha_g, mha_b);
  k_gemm_mfma<0,2><<<gQKV, blk, 0, stream>>>(lnPb, WTb, bias_qkv, nullptr,nullptr, nullptr, qkv, nullptr, rowsP, NQKV, ND);
  k_qkt_mfma<<<dim3(4,4,64), blk, 0, stream>>>(qkv, SCb);
  k_bmsm_mfma<<<512, 256, 0, stream>>>(SCb, qkv, pos, Pb);
  k_pv_mfma<<<dim3(8,64), blk, 0, stream>>>(Pb, qkv, s5b);
  k_gemm_mfma<0,1><<<gPool1, blk, 0, stream>>>(s5b, woT, bo, nullptr,nullptr, nullptr, s6b, nullptr, rowsP, ND, ND);
  // gate + residual, fused pool4 out -> poolRaw (feeds g1 LN directly)
  k_gemm_mfma<1,2><<<gFull2, blk, 0, stream>>>(xbA, egaT, ega_bg, xbA, s6b, nullptr, xbB, poolRaw, rowsF, ND, ND);

  // ================= GCFN global (g1) =================
  k_lnb4<<<rowsP/4, blk, 0, stream>>>(poolRaw, lnPb, g1_ln_g, g1_ln_b);
  k_glu_mfma<<<dim3(24,32), blk, 0, stream>>>(lnPb, g1w1T, g1_b1, glu_p, rowsP, 1536, ND);
  k_gemm_mfma<0,1><<<gPool1, blk, 0, stream>>>(glu_p, g1w2T, g1_b2, nullptr,nullptr, nullptr, s6b, nullptr, rowsP, ND, 1536);
  k_gemm_mfma<1,2><<<gFull2, blk, 0, stream>>>(xbB, g1wgT, g1_bg, xbB, s6b, nullptr, xbA, nullptr, rowsF, ND, ND);

  // ================= CLA =================
  k_lnb4<<<rowsF/4, blk, 0, stream>>>(xbA, lnFb, cla_ln_g, cla_ln_b);
  k_glu_mfma<<<dim3(8,128), blk, 0, stream>>>(lnFb, claw1T, cla_b1, glu_b, rowsF, 512, ND);
  k_dwconv<<<dim3(8, NT/64, NB), blk, 0, stream>>>(glu_b, dw_w, dw_b, conv_b);
  // residual add, fused pool4 out -> poolRaw (feeds g2 LN directly)
  k_gemm_mfma<2,2><<<gFull2, blk, 0, stream>>>(conv_b, claw2T, cla_b2, xbA, nullptr, nullptr, xbB, poolRaw, rowsF, ND, ND);

  // ================= GCFN local (g2) =================
  k_lnb4<<<rowsP/4, blk, 0, stream>>>(poolRaw, lnPb, g2_ln_g, g2_ln_b);
  k_glu_mfma<<<dim3(24,32), blk, 0, stream>>>(lnPb, g2w1T, g2_b1, glu_p, rowsP, 1536, ND);
  k_gemm_mfma<0,1><<<gPool1, blk, 0, stream>>>(glu_p, g2w2T, g2_b2, nullptr,nullptr, nullptr, s6b, nullptr, rowsP, ND, 1536);
  k_gemm_mfma<1,2><<<gFull2, blk, 0, stream>>>(xbB, g2wgT, g2_bg, xbB, s6b, xo, nullptr, nullptr, rowsF, ND, ND);
}